// Round 1
// baseline (602.717 us; speedup 1.0000x reference)
//
#include <hip/hip_runtime.h>
#include <hip/hip_bf16.h>
#include <stdint.h>

#define BATCH 16384
#define MARK  1024
#define NF    40
#define FE    16
#define KDIM  2688      // 2*1024 + 40*16
#define HID   4096
#define BK    32
#define KT    (KDIM / BK)   // 84

typedef __bf16 bf16x8 __attribute__((ext_vector_type(8)));
typedef float  f32x4  __attribute__((ext_vector_type(4)));

static __device__ __forceinline__ unsigned short f2bf(float f) {
  // round-to-nearest-even fp32 -> bf16
  union { float f; uint32_t u; } v; v.f = f;
  uint32_t u = v.u;
  uint32_t r = (u + 0x7FFFu + ((u >> 16) & 1u)) >> 16;
  return (unsigned short)r;
}

// Build bf16 concat row: [emb_i(1024) | emb_a(1024) | feats(640)]
__global__ __launch_bounds__(256) void build_concat(
    const float* __restrict__ emb_i, const float* __restrict__ emb_a,
    const int* __restrict__ mask, const float* __restrict__ fon,
    const float* __restrict__ foff, unsigned short* __restrict__ out) {
  const int b = blockIdx.x;
  const float4* ri = (const float4*)(emb_i + (size_t)b * MARK);
  const float4* ra = (const float4*)(emb_a + (size_t)b * MARK);
  const int* mrow = mask + b * NF;
  unsigned short* orow = out + (size_t)b * KDIM;
  for (int g = threadIdx.x; g < KDIM / 4; g += 256) {
    const int base = g * 4;
    float4 v;
    if (base < MARK) {
      v = ri[g];
    } else if (base < 2 * MARK) {
      v = ra[g - MARK / 4];
    } else {
      const int idx = base - 2 * MARK;
      const int f = idx >> 4;
      const float* tab = (mrow[f] > 0) ? fon : foff;
      v = *(const float4*)(tab + f * FE + (idx & 15));
    }
    ushort4 o;
    o.x = f2bf(v.x); o.y = f2bf(v.y); o.z = f2bf(v.z); o.w = f2bf(v.w);
    *(ushort4*)(orow + base) = o;
  }
}

__global__ __launch_bounds__(256) void convert_w1(
    const float* __restrict__ w, unsigned short* __restrict__ o, int n4) {
  const int stride = gridDim.x * 256;
  for (int i = blockIdx.x * 256 + threadIdx.x; i < n4; i += stride) {
    float4 v = ((const float4*)w)[i];
    ushort4 u;
    u.x = f2bf(v.x); u.y = f2bf(v.y); u.z = f2bf(v.z); u.w = f2bf(v.w);
    ((ushort4*)o)[i] = u;
  }
}

__global__ __launch_bounds__(256) void out_init(float* __restrict__ out,
                                                const float* __restrict__ b2) {
  const int i = blockIdx.x * 256 + threadIdx.x;
  if (i < BATCH) out[i] = b2[0];
}

#define GL16(g, l)                                                              \
  __builtin_amdgcn_global_load_lds(                                             \
      (const __attribute__((address_space(1))) void*)(g),                       \
      (__attribute__((address_space(3))) void*)(l), 16, 0, 0)

// C-tile 128x128, 4 waves (2x2 of 64x64), 16x16x32 bf16 MFMA, fused
// relu(.+b1)*w2 reduction into out[] via atomics.
__global__ __launch_bounds__(256, 2) void gemm_fused(
    const unsigned short* __restrict__ A,   // [BATCH, KDIM] bf16
    const unsigned short* __restrict__ Wb,  // [HID, KDIM]  bf16
    const float* __restrict__ b1,
    const float* __restrict__ w2,
    float* __restrict__ out) {
  __shared__ unsigned short lds_a[2][128 * BK];
  __shared__ unsigned short lds_b[2][128 * BK];

  const int tid  = threadIdx.x;
  const int wid  = tid >> 6;
  const int lane = tid & 63;

  const int bid    = blockIdx.x;
  const int tile_n = bid & 31;   // 32 tiles over HID
  const int tile_m = bid >> 5;   // 128 tiles over BATCH

  // ---- staging: wave w loads chunks {2w, 2w+1} (16 rows each) of A and B
  const int srow  = (wid << 5) + (lane >> 2);  // 2w*16 + lane/4
  const int skoff = (lane & 3) * 8;
  const unsigned short* pA0 = A + (size_t)(tile_m * 128 + srow) * KDIM + skoff;
  const unsigned short* pA1 = pA0 + (size_t)16 * KDIM;
  const unsigned short* pB0 = Wb + (size_t)(tile_n * 128 + srow) * KDIM + skoff;
  const unsigned short* pB1 = pB0 + (size_t)16 * KDIM;
  const int lco = wid * 1024;  // wave's LDS chunk base (elements)

  GL16(pA0, &lds_a[0][lco]);
  GL16(pA1, &lds_a[0][lco + 512]);
  GL16(pB0, &lds_b[0][lco]);
  GL16(pB1, &lds_b[0][lco + 512]);
  pA0 += BK; pA1 += BK; pB0 += BK; pB1 += BK;

  const int wave_m = wid >> 1, wave_n = wid & 1;
  const int fr = lane & 15, k8 = lane >> 4;
  const int aoff = (wave_m * 64 + fr) * BK + k8 * 8;
  const int boff = (wave_n * 64 + fr) * BK + k8 * 8;

  f32x4 acc[4][4];
#pragma unroll
  for (int m = 0; m < 4; ++m)
#pragma unroll
    for (int n = 0; n < 4; ++n) acc[m][n] = (f32x4){0.f, 0.f, 0.f, 0.f};

  int buf = 0;
  for (int kt = 0; kt < KT; ++kt) {
    __syncthreads();
    if (kt + 1 < KT) {
      GL16(pA0, &lds_a[buf ^ 1][lco]);
      GL16(pA1, &lds_a[buf ^ 1][lco + 512]);
      GL16(pB0, &lds_b[buf ^ 1][lco]);
      GL16(pB1, &lds_b[buf ^ 1][lco + 512]);
      pA0 += BK; pA1 += BK; pB0 += BK; pB1 += BK;
    }
    bf16x8 af[4], bfr[4];
#pragma unroll
    for (int m = 0; m < 4; ++m)
      af[m] = *reinterpret_cast<const bf16x8*>(&lds_a[buf][aoff + m * 16 * BK]);
#pragma unroll
    for (int n = 0; n < 4; ++n)
      bfr[n] = *reinterpret_cast<const bf16x8*>(&lds_b[buf][boff + n * 16 * BK]);
#pragma unroll
    for (int m = 0; m < 4; ++m)
#pragma unroll
      for (int n = 0; n < 4; ++n)
        acc[m][n] = __builtin_amdgcn_mfma_f32_16x16x32_bf16(af[m], bfr[n],
                                                            acc[m][n], 0, 0, 0);
    buf ^= 1;
  }

  // ---- fused epilogue: out[row] += sum_cols relu(acc + b1[col]) * w2[col]
  float b1v[4], w2v[4];
  const int gcol_base = tile_n * 128 + wave_n * 64 + fr;
#pragma unroll
  for (int n = 0; n < 4; ++n) {
    b1v[n] = b1[gcol_base + n * 16];
    w2v[n] = w2[gcol_base + n * 16];
  }
  const int grow_base = tile_m * 128 + wave_m * 64 + k8 * 4;
#pragma unroll
  for (int m = 0; m < 4; ++m) {
    float vs[4] = {0.f, 0.f, 0.f, 0.f};
#pragma unroll
    for (int n = 0; n < 4; ++n) {
      f32x4 a = acc[m][n];
#pragma unroll
      for (int j = 0; j < 4; ++j) {
        float h = a[j] + b1v[n];
        h = h > 0.f ? h : 0.f;
        vs[j] = fmaf(h, w2v[n], vs[j]);
      }
    }
#pragma unroll
    for (int j = 0; j < 4; ++j) {
      vs[j] += __shfl_xor(vs[j], 1, 16);
      vs[j] += __shfl_xor(vs[j], 2, 16);
      vs[j] += __shfl_xor(vs[j], 4, 16);
      vs[j] += __shfl_xor(vs[j], 8, 16);
    }
    if (fr == 0) {
#pragma unroll
      for (int j = 0; j < 4; ++j)
        atomicAdd(&out[grow_base + m * 16 + j], vs[j]);
    }
  }
}

extern "C" void kernel_launch(void* const* d_in, const int* in_sizes, int n_in,
                              void* d_out, int out_size, void* d_ws, size_t ws_size,
                              hipStream_t stream) {
  const float* emb_i = (const float*)d_in[0];
  const float* emb_a = (const float*)d_in[1];
  const int*   fmask = (const int*)d_in[2];
  const float* fon   = (const float*)d_in[3];
  const float* foff  = (const float*)d_in[4];
  const float* W1    = (const float*)d_in[5];
  const float* b1    = (const float*)d_in[6];
  const float* W2    = (const float*)d_in[7];
  const float* b2    = (const float*)d_in[8];
  float* out = (float*)d_out;

  unsigned short* concat = (unsigned short*)d_ws;                 // BATCH*KDIM bf16
  unsigned short* w1b    = concat + (size_t)BATCH * KDIM;         // HID*KDIM bf16

  build_concat<<<BATCH, 256, 0, stream>>>(emb_i, emb_a, fmask, fon, foff, concat);
  convert_w1<<<2048, 256, 0, stream>>>(W1, w1b, HID * KDIM / 4);
  out_init<<<BATCH / 256, 256, 0, stream>>>(out, b2);
  gemm_fused<<<(BATCH / 128) * (HID / 128), 256, 0, stream>>>(concat, w1b, b1,
                                                              W2, out);
}

// Round 2
// 541.595 us; speedup vs baseline: 1.1129x; 1.1129x over previous
//
#include <hip/hip_runtime.h>
#include <hip/hip_bf16.h>
#include <stdint.h>

#define BATCH 16384
#define MARK  1024
#define NF    40
#define FE    16
#define KDIM  2688      // 2*1024 + 40*16
#define HID   4096
#define BK    64
#define NKT   (KDIM / BK)   // 42 K-tiles, 21 iterations x 2

typedef __bf16 bf16x8 __attribute__((ext_vector_type(8)));
typedef float  f32x4  __attribute__((ext_vector_type(4)));

static __device__ __forceinline__ unsigned short f2bf(float f) {
  union { float f; uint32_t u; } v; v.f = f;
  uint32_t u = v.u;
  uint32_t r = (u + 0x7FFFu + ((u >> 16) & 1u)) >> 16;
  return (unsigned short)r;
}

__global__ __launch_bounds__(256) void build_concat(
    const float* __restrict__ emb_i, const float* __restrict__ emb_a,
    const int* __restrict__ mask, const float* __restrict__ fon,
    const float* __restrict__ foff, unsigned short* __restrict__ out) {
  const int b = blockIdx.x;
  const float4* ri = (const float4*)(emb_i + (size_t)b * MARK);
  const float4* ra = (const float4*)(emb_a + (size_t)b * MARK);
  const int* mrow = mask + b * NF;
  unsigned short* orow = out + (size_t)b * KDIM;
  for (int g = threadIdx.x; g < KDIM / 4; g += 256) {
    const int base = g * 4;
    float4 v;
    if (base < MARK) {
      v = ri[g];
    } else if (base < 2 * MARK) {
      v = ra[g - MARK / 4];
    } else {
      const int idx = base - 2 * MARK;
      const int f = idx >> 4;
      const float* tab = (mrow[f] > 0) ? fon : foff;
      v = *(const float4*)(tab + f * FE + (idx & 15));
    }
    ushort4 o;
    o.x = f2bf(v.x); o.y = f2bf(v.y); o.z = f2bf(v.z); o.w = f2bf(v.w);
    *(ushort4*)(orow + base) = o;
  }
}

__global__ __launch_bounds__(256) void convert_w1(
    const float* __restrict__ w, unsigned short* __restrict__ o, int n4) {
  const int stride = gridDim.x * 256;
  for (int i = blockIdx.x * 256 + threadIdx.x; i < n4; i += stride) {
    float4 v = ((const float4*)w)[i];
    ushort4 u;
    u.x = f2bf(v.x); u.y = f2bf(v.y); u.z = f2bf(v.z); u.w = f2bf(v.w);
    ((ushort4*)o)[i] = u;
  }
}

__global__ __launch_bounds__(256) void out_init(float* __restrict__ out,
                                                const float* __restrict__ b2) {
  const int i = blockIdx.x * 256 + threadIdx.x;
  if (i < BATCH) out[i] = b2[0];
}

#define GL16(g, l)                                                              \
  __builtin_amdgcn_global_load_lds(                                             \
      (const __attribute__((address_space(1))) void*)(g),                       \
      (__attribute__((address_space(3))) void*)(l), 16, 0, 0)

#define BAR()        __builtin_amdgcn_s_barrier()
#define WAIT_LGKM0() asm volatile("s_waitcnt lgkmcnt(0)" ::: "memory")
#define WAIT_VM6()   asm volatile("s_waitcnt vmcnt(6)" ::: "memory")

// 256x256 tile, BK=64, 8 waves (2M x 4N), 8-phase schedule with counted vmcnt.
// LDS XOR-swizzle (16B-chunk granularity): stored chunk cs of row r holds
// source chunk cs ^ (r&7); reads apply the same XOR. global_load_lds writes
// linearly, so the swizzle is applied on the per-lane GLOBAL source address.
__global__ __launch_bounds__(512, 2) void gemm_fused(
    const unsigned short* __restrict__ A,   // [BATCH, KDIM] bf16
    const unsigned short* __restrict__ Wb,  // [HID, KDIM]  bf16
    const float* __restrict__ b1,
    const float* __restrict__ w2,
    float* __restrict__ out) {
  __shared__ unsigned short sA[2][256 * BK];   // 64 KB
  __shared__ unsigned short sB[2][256 * BK];   // 64 KB
  __shared__ float spart[2][4][128];           // 4 KB cross-wave reduce

  const int tid  = threadIdx.x;
  const int wid  = tid >> 6;
  const int lane = tid & 63;
  const int fr   = lane & 15;   // MFMA fragment row index
  const int k8   = lane >> 4;   // MFMA k-chunk selector (0..3)
  const int wm   = wid >> 2;    // wave M index (0..1)
  const int wn   = wid & 3;     // wave N index (0..3)

  const int tile_n = blockIdx.x & 15;   // 16 tiles over HID
  const int tile_m = blockIdx.x >> 4;   // 64 tiles over BATCH

  // staging lane constants: lane l writes LDS row r0 + (l>>3), 16B-chunk (l&7);
  // source chunk = (l&7) ^ (l>>3)  (row&7 == l>>3 since r0 % 8 == 0)
  const int lrow = lane >> 3;
  const int lsrc = ((lane & 7) ^ lrow) * 8;   // elements
  const unsigned short* Aptr =
      A + ((size_t)tile_m * 256 + lrow) * KDIM + lsrc;
  const unsigned short* Bptr =
      Wb + ((size_t)tile_n * 256 + lrow) * KDIM + lsrc;

  // read-side swizzled chunk offsets (elements) for kk=0/1
  const int swz0 = ((k8 ^ (fr & 7)) * 8);
  const int swz1 = (((4 + k8) ^ (fr & 7)) * 8);

// A unit MH: rows {g*128 + MH*64 + wid*8}, 2 gloads/wave
#define STAGEA(BUF, MH, KT)                                                    \
  { _Pragma("unroll") for (int g = 0; g < 2; ++g) {                            \
      const int r0 = g * 128 + (MH)*64 + wid * 8;                              \
      GL16(Aptr + (size_t)r0 * KDIM + (KT)*BK, &sA[BUF][r0 * BK]); } }

// B unit NH: rows {g*128 + (wid>>2)*64 + NH*32 + (wid&3)*8}
#define STAGEB(BUF, NH, KT)                                                    \
  { _Pragma("unroll") for (int g = 0; g < 2; ++g) {                            \
      const int r0 = g * 128 + (wid >> 2) * 64 + (NH)*32 + (wid & 3) * 8;      \
      GL16(Bptr + (size_t)r0 * KDIM + (KT)*BK, &sB[BUF][r0 * BK]); } }

#define LOADA(BUF, MH)                                                         \
  { _Pragma("unroll") for (int i = 0; i < 4; ++i) {                            \
      const unsigned short* p =                                                \
          &sA[BUF][(wm * 128 + (MH)*64 + i * 16 + fr) * BK];                   \
      af[i][0] = *(const bf16x8*)(p + swz0);                                   \
      af[i][1] = *(const bf16x8*)(p + swz1); } }

#define LOADB(BUF, NH)                                                         \
  { _Pragma("unroll") for (int j = 0; j < 2; ++j) {                            \
      const unsigned short* p =                                                \
          &sB[BUF][(wn * 64 + (NH)*32 + j * 16 + fr) * BK];                    \
      bfr[j][0] = *(const bf16x8*)(p + swz0);                                  \
      bfr[j][1] = *(const bf16x8*)(p + swz1); } }

#define MMA(MH, NH)                                                            \
  { __builtin_amdgcn_s_setprio(1);                                             \
    _Pragma("unroll") for (int i = 0; i < 4; ++i)                              \
    _Pragma("unroll") for (int j = 0; j < 2; ++j) {                            \
      acc[(MH)*4 + i][(NH)*2 + j] = __builtin_amdgcn_mfma_f32_16x16x32_bf16(   \
          af[i][0], bfr[j][0], acc[(MH)*4 + i][(NH)*2 + j], 0, 0, 0);          \
      acc[(MH)*4 + i][(NH)*2 + j] = __builtin_amdgcn_mfma_f32_16x16x32_bf16(   \
          af[i][1], bfr[j][1], acc[(MH)*4 + i][(NH)*2 + j], 0, 0, 0); }        \
    __builtin_amdgcn_s_setprio(0); }

  f32x4 acc[8][4];
#pragma unroll
  for (int i = 0; i < 8; ++i)
#pragma unroll
    for (int j = 0; j < 4; ++j) acc[i][j] = (f32x4){0.f, 0.f, 0.f, 0.f};
  bf16x8 af[4][2], bfr[2][2];

  // hoist epilogue params (tiny, L2-resident)
  float b1v[4], w2v[4];
  const int gcol = tile_n * 256 + wn * 64 + fr;
#pragma unroll
  for (int j = 0; j < 4; ++j) {
    b1v[j] = b1[gcol + j * 16];
    w2v[j] = w2[gcol + j * 16];
  }

  // ---- prologue: tile0 fully (U1..U4), tile1 U1..U3 (U4(t1) issued at P1)
  STAGEA(0, 0, 0); STAGEB(0, 1, 0); STAGEA(0, 1, 0); STAGEB(0, 0, 0);
  STAGEA(1, 0, 1); STAGEB(1, 1, 1); STAGEA(1, 1, 1);
  WAIT_VM6();   // tile0's 8 loads landed; tile1's 6 in flight
  BAR();

#pragma unroll 1
  for (int t = 0; t < NKT; t += 2) {
    int t2 = t + 2; if (t2 >= NKT) t2 -= NKT;   // wrapped prefetch keeps
    int t3 = t + 3; if (t3 >= NKT) t3 -= NKT;   // vmcnt counts uniform
    // P1: Q(mh0,nh0) of even tile (buf0)
    LOADA(0, 0); LOADB(0, 0);
    STAGEB(1, 0, t + 1);                 // buf1 B-nh0 freed at prev P8
    BAR(); WAIT_LGKM0();
    MMA(0, 0);
    BAR();
    // P2: Q(mh0,nh1)
    LOADB(0, 1);
    STAGEA(0, 0, t2);                    // buf0 A-mh0 freed at P1
    BAR(); WAIT_LGKM0();
    MMA(0, 1);
    BAR();
    // P3: Q(mh1,nh1)
    LOADA(0, 1);
    STAGEB(0, 1, t2);                    // buf0 B-nh1 freed at P2
    BAR(); WAIT_LGKM0();
    MMA(1, 1);
    BAR();
    // P4: Q(mh1,nh0)
    LOADB(0, 0);
    STAGEA(0, 1, t2);                    // buf0 A-mh1 freed at P3
    BAR(); WAIT_LGKM0();
    MMA(1, 0);
    WAIT_VM6();                          // guarantees odd tile fully landed
    BAR();
    // P5: Q(mh0,nh0) of odd tile (buf1)
    LOADA(1, 0); LOADB(1, 0);
    STAGEB(0, 0, t2);                    // buf0 B-nh0 freed at P4
    BAR(); WAIT_LGKM0();
    MMA(0, 0);
    BAR();
    // P6
    LOADB(1, 1);
    STAGEA(1, 0, t3);                    // buf1 A-mh0 freed at P5
    BAR(); WAIT_LGKM0();
    MMA(0, 1);
    BAR();
    // P7
    LOADA(1, 1);
    STAGEB(1, 1, t3);                    // buf1 B-nh1 freed at P6
    BAR(); WAIT_LGKM0();
    MMA(1, 1);
    BAR();
    // P8
    LOADB(1, 0);
    STAGEA(1, 1, t3);                    // buf1 A-mh1 freed at P7
    BAR(); WAIT_LGKM0();
    MMA(1, 0);
    WAIT_VM6();                          // guarantees next even tile landed
    BAR();
  }

  // ---- fused epilogue: out[row] += sum_cols relu(acc + b1[col]) * w2[col]
  // C/D layout: col = fr, row = k8*4 + reg
#pragma unroll
  for (int i = 0; i < 8; ++i) {
    float vs[4];
#pragma unroll
    for (int r = 0; r < 4; ++r) {
      float s = 0.f;
#pragma unroll
      for (int j = 0; j < 4; ++j) {
        float h = acc[i][j][r] + b1v[j];
        h = h > 0.f ? h : 0.f;
        s = fmaf(h, w2v[j], s);
      }
      vs[r] = s;
    }
#pragma unroll
    for (int r = 0; r < 4; ++r) {
      vs[r] += __shfl_xor(vs[r], 1, 16);
      vs[r] += __shfl_xor(vs[r], 2, 16);
      vs[r] += __shfl_xor(vs[r], 4, 16);
      vs[r] += __shfl_xor(vs[r], 8, 16);
    }
    if (fr == 0) {
#pragma unroll
      for (int r = 0; r < 4; ++r)
        spart[wm][wn][i * 16 + k8 * 4 + r] = vs[r];
    }
  }
  __syncthreads();
  if (tid < 256) {
    const int rl = tid & 127, wmr = tid >> 7;
    float s = spart[wmr][0][rl] + spart[wmr][1][rl] +
              spart[wmr][2][rl] + spart[wmr][3][rl];
    atomicAdd(&out[(size_t)tile_m * 256 + tid], s);
  }
}

extern "C" void kernel_launch(void* const* d_in, const int* in_sizes, int n_in,
                              void* d_out, int out_size, void* d_ws, size_t ws_size,
                              hipStream_t stream) {
  const float* emb_i = (const float*)d_in[0];
  const float* emb_a = (const float*)d_in[1];
  const int*   fmask = (const int*)d_in[2];
  const float* fon   = (const float*)d_in[3];
  const float* foff  = (const float*)d_in[4];
  const float* W1    = (const float*)d_in[5];
  const float* b1    = (const float*)d_in[6];
  const float* W2    = (const float*)d_in[7];
  const float* b2    = (const float*)d_in[8];
  float* out = (float*)d_out;

  unsigned short* concat = (unsigned short*)d_ws;                 // BATCH*KDIM bf16
  unsigned short* w1b    = concat + (size_t)BATCH * KDIM;         // HID*KDIM bf16

  build_concat<<<BATCH, 256, 0, stream>>>(emb_i, emb_a, fmask, fon, foff, concat);
  convert_w1<<<2048, 256, 0, stream>>>(W1, w1b, HID * KDIM / 4);
  out_init<<<BATCH / 256, 256, 0, stream>>>(out, b2);
  gemm_fused<<<(BATCH / 256) * (HID / 256), 512, 0, stream>>>(concat, w1b, b1,
                                                              W2, out);
}

// Round 3
// 540.581 us; speedup vs baseline: 1.1149x; 1.0019x over previous
//
#include <hip/hip_runtime.h>
#include <hip/hip_bf16.h>
#include <stdint.h>

#define BATCH 16384
#define MARK  1024
#define NF    40
#define FE    16
#define KDIM  2688      // 2*1024 + 40*16
#define HID   4096
#define BK    64
#define NKT   (KDIM / BK)   // 42 K-tiles, 21 iterations x 2

typedef __bf16 bf16x8 __attribute__((ext_vector_type(8)));
typedef float  f32x4  __attribute__((ext_vector_type(4)));

static __device__ __forceinline__ unsigned short f2bf(float f) {
  union { float f; uint32_t u; } v; v.f = f;
  uint32_t u = v.u;
  uint32_t r = (u + 0x7FFFu + ((u >> 16) & 1u)) >> 16;
  return (unsigned short)r;
}

__global__ __launch_bounds__(256) void build_concat(
    const float* __restrict__ emb_i, const float* __restrict__ emb_a,
    const int* __restrict__ mask, const float* __restrict__ fon,
    const float* __restrict__ foff, unsigned short* __restrict__ out) {
  const int b = blockIdx.x;
  const float4* ri = (const float4*)(emb_i + (size_t)b * MARK);
  const float4* ra = (const float4*)(emb_a + (size_t)b * MARK);
  const int* mrow = mask + b * NF;
  unsigned short* orow = out + (size_t)b * KDIM;
  for (int g = threadIdx.x; g < KDIM / 4; g += 256) {
    const int base = g * 4;
    float4 v;
    if (base < MARK) {
      v = ri[g];
    } else if (base < 2 * MARK) {
      v = ra[g - MARK / 4];
    } else {
      const int idx = base - 2 * MARK;
      const int f = idx >> 4;
      const float* tab = (mrow[f] > 0) ? fon : foff;
      v = *(const float4*)(tab + f * FE + (idx & 15));
    }
    ushort4 o;
    o.x = f2bf(v.x); o.y = f2bf(v.y); o.z = f2bf(v.z); o.w = f2bf(v.w);
    *(ushort4*)(orow + base) = o;
  }
}

__global__ __launch_bounds__(256) void convert_w1(
    const float* __restrict__ w, unsigned short* __restrict__ o, int n4) {
  const int stride = gridDim.x * 256;
  for (int i = blockIdx.x * 256 + threadIdx.x; i < n4; i += stride) {
    float4 v = ((const float4*)w)[i];
    ushort4 u;
    u.x = f2bf(v.x); u.y = f2bf(v.y); u.z = f2bf(v.z); u.w = f2bf(v.w);
    ((ushort4*)o)[i] = u;
  }
}

__global__ __launch_bounds__(256) void out_init(float* __restrict__ out,
                                                const float* __restrict__ b2) {
  const int i = blockIdx.x * 256 + threadIdx.x;
  if (i < BATCH) out[i] = b2[0];
}

#define GL16(g, l)                                                              \
  __builtin_amdgcn_global_load_lds(                                             \
      (const __attribute__((address_space(1))) void*)(g),                       \
      (__attribute__((address_space(3))) void*)(l), 16, 0, 0)

#define BAR()        __builtin_amdgcn_s_barrier()
#define WAIT_LGKM0() asm volatile("s_waitcnt lgkmcnt(0)" ::: "memory")
#define WAIT_VM6()   asm volatile("s_waitcnt vmcnt(6)" ::: "memory")

// 256x256 tile, BK=64, 8 waves (2M x 4N), 8-phase schedule with counted vmcnt.
// LDS XOR-swizzle (16B-chunk granularity): stored chunk cs of row r holds
// source chunk cs ^ (r&7); reads apply the same XOR. global_load_lds writes
// linearly, so the swizzle is applied on the per-lane GLOBAL source address.
// XCD rectangle swizzle: bid->XCD is bid&7 (m09); give each XCD's 32
// co-resident blocks an 8(tile_m) x 4(tile_n) rectangle so A is 4-way and B
// 8-way L2-shared (per-K-tile working set 384 KB << 4 MB L2).
__global__ __launch_bounds__(512, 2) void gemm_fused(
    const unsigned short* __restrict__ A,   // [BATCH, KDIM] bf16
    const unsigned short* __restrict__ Wb,  // [HID, KDIM]  bf16
    const float* __restrict__ b1,
    const float* __restrict__ w2,
    float* __restrict__ out) {
  __shared__ unsigned short sA[2][256 * BK];   // 64 KB
  __shared__ unsigned short sB[2][256 * BK];   // 64 KB
  __shared__ float spart[2][4][128];           // 4 KB cross-wave reduce

  const int tid  = threadIdx.x;
  const int wid  = tid >> 6;
  const int lane = tid & 63;
  const int fr   = lane & 15;   // MFMA fragment row index
  const int k8   = lane >> 4;   // MFMA k-chunk selector (0..3)
  const int wm   = wid >> 2;    // wave M index (0..1)
  const int wn   = wid & 3;     // wave N index (0..3)

  // ---- XCD rectangle swizzle (bijective over 1024 = 8 x 4 x 8 x 4)
  const int bid = blockIdx.x;
  const int xcd = bid & 7;
  const int j   = bid >> 3;        // dispatch order within XCD, 0..127
  const int sub = j >> 5;          // sub-round 0..3
  const int sm  = (j >> 2) & 7;
  const int sn  = j & 3;
  const int tile_m = (xcd >> 1) * 16 + (sub >> 1) * 8 + sm;   // 0..63
  const int tile_n = (xcd & 1) * 8 + (sub & 1) * 4 + sn;      // 0..15

  // staging lane constants: lane l writes LDS row r0 + (l>>3), 16B-chunk (l&7);
  // source chunk = (l&7) ^ (l>>3)  (row&7 == l>>3 since r0 % 8 == 0)
  const int lrow = lane >> 3;
  const int lsrc = ((lane & 7) ^ lrow) * 8;   // elements
  const unsigned short* Aptr =
      A + ((size_t)tile_m * 256 + lrow) * KDIM + lsrc;
  const unsigned short* Bptr =
      Wb + ((size_t)tile_n * 256 + lrow) * KDIM + lsrc;

  // read-side swizzled chunk offsets (elements) for kk=0/1
  const int swz0 = ((k8 ^ (fr & 7)) * 8);
  const int swz1 = (((4 + k8) ^ (fr & 7)) * 8);

// A unit MH: rows {g*128 + MH*64 + wid*8}, 2 gloads/wave
#define STAGEA(BUF, MH, KT)                                                    \
  { _Pragma("unroll") for (int g = 0; g < 2; ++g) {                            \
      const int r0 = g * 128 + (MH)*64 + wid * 8;                              \
      GL16(Aptr + (size_t)r0 * KDIM + (KT)*BK, &sA[BUF][r0 * BK]); } }

// B unit NH: rows {g*128 + (wid>>2)*64 + NH*32 + (wid&3)*8}
#define STAGEB(BUF, NH, KT)                                                    \
  { _Pragma("unroll") for (int g = 0; g < 2; ++g) {                            \
      const int r0 = g * 128 + (wid >> 2) * 64 + (NH)*32 + (wid & 3) * 8;      \
      GL16(Bptr + (size_t)r0 * KDIM + (KT)*BK, &sB[BUF][r0 * BK]); } }

#define LOADA(BUF, MH)                                                         \
  { _Pragma("unroll") for (int i = 0; i < 4; ++i) {                            \
      const unsigned short* p =                                                \
          &sA[BUF][(wm * 128 + (MH)*64 + i * 16 + fr) * BK];                   \
      af[i][0] = *(const bf16x8*)(p + swz0);                                   \
      af[i][1] = *(const bf16x8*)(p + swz1); } }

#define LOADB(BUF, NH)                                                         \
  { _Pragma("unroll") for (int j = 0; j < 2; ++j) {                            \
      const unsigned short* p =                                                \
          &sB[BUF][(wn * 64 + (NH)*32 + j * 16 + fr) * BK];                    \
      bfr[j][0] = *(const bf16x8*)(p + swz0);                                  \
      bfr[j][1] = *(const bf16x8*)(p + swz1); } }

#define MMA(MH, NH)                                                            \
  { __builtin_amdgcn_s_setprio(1);                                             \
    _Pragma("unroll") for (int i = 0; i < 4; ++i)                              \
    _Pragma("unroll") for (int j = 0; j < 2; ++j) {                            \
      acc[(MH)*4 + i][(NH)*2 + j] = __builtin_amdgcn_mfma_f32_16x16x32_bf16(   \
          af[i][0], bfr[j][0], acc[(MH)*4 + i][(NH)*2 + j], 0, 0, 0);          \
      acc[(MH)*4 + i][(NH)*2 + j] = __builtin_amdgcn_mfma_f32_16x16x32_bf16(   \
          af[i][1], bfr[j][1], acc[(MH)*4 + i][(NH)*2 + j], 0, 0, 0); }        \
    __builtin_amdgcn_s_setprio(0); }

  f32x4 acc[8][4];
#pragma unroll
  for (int i = 0; i < 8; ++i)
#pragma unroll
    for (int j = 0; j < 4; ++j) acc[i][j] = (f32x4){0.f, 0.f, 0.f, 0.f};
  bf16x8 af[4][2], bfr[2][2];

  // hoist epilogue params (tiny, L2-resident)
  float b1v[4], w2v[4];
  const int gcol = tile_n * 256 + wn * 64 + fr;
#pragma unroll
  for (int jj = 0; jj < 4; ++jj) {
    b1v[jj] = b1[gcol + jj * 16];
    w2v[jj] = w2[gcol + jj * 16];
  }

  // ---- prologue: tile0 fully (U1..U4), tile1 U1..U3 (U4(t1) issued at P1)
  STAGEA(0, 0, 0); STAGEB(0, 1, 0); STAGEA(0, 1, 0); STAGEB(0, 0, 0);
  STAGEA(1, 0, 1); STAGEB(1, 1, 1); STAGEA(1, 1, 1);
  WAIT_VM6();   // tile0's 8 loads landed; tile1's 6 in flight
  BAR();

#pragma unroll 1
  for (int t = 0; t < NKT; t += 2) {
    int t2 = t + 2; if (t2 >= NKT) t2 -= NKT;   // wrapped prefetch keeps
    int t3 = t + 3; if (t3 >= NKT) t3 -= NKT;   // vmcnt counts uniform
    // P1: Q(mh0,nh0) of even tile (buf0)
    LOADA(0, 0); LOADB(0, 0);
    STAGEB(1, 0, t + 1);                 // buf1 B-nh0 freed at prev P8
    BAR(); WAIT_LGKM0();
    MMA(0, 0);
    BAR();
    // P2: Q(mh0,nh1)
    LOADB(0, 1);
    STAGEA(0, 0, t2);                    // buf0 A-mh0 freed at P1
    BAR(); WAIT_LGKM0();
    MMA(0, 1);
    BAR();
    // P3: Q(mh1,nh1)
    LOADA(0, 1);
    STAGEB(0, 1, t2);                    // buf0 B-nh1 freed at P2
    BAR(); WAIT_LGKM0();
    MMA(1, 1);
    BAR();
    // P4: Q(mh1,nh0)
    LOADB(0, 0);
    STAGEA(0, 1, t2);                    // buf0 A-mh1 freed at P3
    BAR(); WAIT_LGKM0();
    MMA(1, 0);
    WAIT_VM6();                          // guarantees odd tile fully landed
    BAR();
    // P5: Q(mh0,nh0) of odd tile (buf1)
    LOADA(1, 0); LOADB(1, 0);
    STAGEB(0, 0, t2);                    // buf0 B-nh0 freed at P4
    BAR(); WAIT_LGKM0();
    MMA(0, 0);
    BAR();
    // P6
    LOADB(1, 1);
    STAGEA(1, 0, t3);                    // buf1 A-mh0 freed at P5
    BAR(); WAIT_LGKM0();
    MMA(0, 1);
    BAR();
    // P7
    LOADA(1, 1);
    STAGEB(1, 1, t3);                    // buf1 B-nh1 freed at P6
    BAR(); WAIT_LGKM0();
    MMA(1, 1);
    BAR();
    // P8
    LOADB(1, 0);
    STAGEA(1, 1, t3);                    // buf1 A-mh1 freed at P7
    BAR(); WAIT_LGKM0();
    MMA(1, 0);
    WAIT_VM6();                          // guarantees next even tile landed
    BAR();
  }

  // ---- fused epilogue: out[row] += sum_cols relu(acc + b1[col]) * w2[col]
  // C/D layout: col = fr, row = k8*4 + reg
#pragma unroll
  for (int i = 0; i < 8; ++i) {
    float vs[4];
#pragma unroll
    for (int r = 0; r < 4; ++r) {
      float s = 0.f;
#pragma unroll
      for (int jj = 0; jj < 4; ++jj) {
        float h = acc[i][jj][r] + b1v[jj];
        h = h > 0.f ? h : 0.f;
        s = fmaf(h, w2v[jj], s);
      }
      vs[r] = s;
    }
#pragma unroll
    for (int r = 0; r < 4; ++r) {
      vs[r] += __shfl_xor(vs[r], 1, 16);
      vs[r] += __shfl_xor(vs[r], 2, 16);
      vs[r] += __shfl_xor(vs[r], 4, 16);
      vs[r] += __shfl_xor(vs[r], 8, 16);
    }
    if (fr == 0) {
#pragma unroll
      for (int r = 0; r < 4; ++r)
        spart[wm][wn][i * 16 + k8 * 4 + r] = vs[r];
    }
  }
  __syncthreads();
  if (tid < 256) {
    const int rl = tid & 127, wmr = tid >> 7;
    float s = spart[wmr][0][rl] + spart[wmr][1][rl] +
              spart[wmr][2][rl] + spart[wmr][3][rl];
    atomicAdd(&out[(size_t)tile_m * 256 + tid], s);
  }
}

extern "C" void kernel_launch(void* const* d_in, const int* in_sizes, int n_in,
                              void* d_out, int out_size, void* d_ws, size_t ws_size,
                              hipStream_t stream) {
  const float* emb_i = (const float*)d_in[0];
  const float* emb_a = (const float*)d_in[1];
  const int*   fmask = (const int*)d_in[2];
  const float* fon   = (const float*)d_in[3];
  const float* foff  = (const float*)d_in[4];
  const float* W1    = (const float*)d_in[5];
  const float* b1    = (const float*)d_in[6];
  const float* W2    = (const float*)d_in[7];
  const float* b2    = (const float*)d_in[8];
  float* out = (float*)d_out;

  unsigned short* concat = (unsigned short*)d_ws;                 // BATCH*KDIM bf16
  unsigned short* w1b    = concat + (size_t)BATCH * KDIM;         // HID*KDIM bf16

  build_concat<<<BATCH, 256, 0, stream>>>(emb_i, emb_a, fmask, fon, foff, concat);
  convert_w1<<<2048, 256, 0, stream>>>(W1, w1b, HID * KDIM / 4);
  out_init<<<BATCH / 256, 256, 0, stream>>>(out, b2);
  gemm_fused<<<(BATCH / 256) * (HID / 256), 512, 0, stream>>>(concat, w1b, b1,
                                                              W2, out);
}